// Round 1
// baseline (166.787 us; speedup 1.0000x reference)
//
#include <hip/hip_runtime.h>

// PointNet fused kernel for MI355X (gfx950).
//
// Key algebraic fact: the segment-MLP contribution and cb are constant per
// bbox row and cancel in the per-row min/max rescale. Output depends only on
//   s1[m,n] = feat[m,n]·cW[0:6] + relu(MLP3(feat[m,n]))·cW[6:262]
// followed by per-row rescale to [-1,1].
//
// Pipeline:
//  k0: pack W1(6x256, K padded to 32), W2, W3 (fp32->bf16) into MFMA
//      fragment order in d_ws (272 KB needed).
//  k1: fused per-128-point-tile: L1 (MFMA, 1 kstep) -> hA(LDS) -> L2 (MFMA,
//      8 ksteps) -> hB(LDS) -> L3 (MFMA) -> dot with cW[6:262] -> + feat·cW[0:6]
//      -> raw s1 to d_out. All GEMMs computed transposed (Z^T = W^T h^T) so
//      epilogue writes are contiguous b64 LDS writes.
//  k2: per-bbox min/max + rescale of d_out in place.

typedef __attribute__((ext_vector_type(8))) short short8;   // 8 bf16 (4 VGPRs)
typedef __attribute__((ext_vector_type(4))) float f32x4;    // MFMA accum

#define THREADS 512

__device__ __forceinline__ unsigned short f2bf(float f) {
  union { float f; unsigned int u; } x; x.f = f;
  unsigned int r = x.u + 0x7fffu + ((x.u >> 16) & 1u);   // round-nearest-even
  return (unsigned short)(r >> 16);
}

// ---------------------------------------------------------------------------
// k0: pack weights into fragment order:
//   idx(s,ct,hi,col,j) = (((s*16+ct)*4+hi)*16+col)*8 + j
//   k = s*32 + hi*8 + j   (zero-padded past Kreal), c = ct*16 + col
// Regions (ushort elems): W1 @0 (8192), W2 @8192 (65536), W3 @73728 (65536)
// ---------------------------------------------------------------------------
__global__ void pn_pack(const float* __restrict__ W1,
                        const float* __restrict__ W2,
                        const float* __restrict__ W3,
                        unsigned short* __restrict__ wp) {
  int e = blockIdx.x * 256 + threadIdx.x;           // 0 .. 139263
  const float* src; int Kreal, base, r;
  if (e < 8192)       { src = W1; Kreal = 6;   base = 0;     r = e; }
  else if (e < 73728) { src = W2; Kreal = 256; base = 8192;  r = e - 8192; }
  else                { src = W3; Kreal = 256; base = 73728; r = e - 73728; }
  int j   = r & 7;
  int col = (r >> 3) & 15;
  int hi  = (r >> 7) & 3;
  int ct  = (r >> 9) & 15;
  int s   = r >> 13;
  int k = s * 32 + hi * 8 + j;
  int c = ct * 16 + col;
  float v = (k < Kreal) ? src[k * 256 + c] : 0.0f;
  wp[base + r] = f2bf(v);
}

// ---------------------------------------------------------------------------
// k1: fused main kernel. One block = 128 points of one bbox. 8 waves.
// Wave (cgrp 0..3, pgrp 0..1): output tile = 64 channels x 64 points.
// ---------------------------------------------------------------------------
template<int KSTEPS, int HSTRIDE, bool SWZ>
__device__ __forceinline__ void gemm_T(const unsigned short* __restrict__ wpL,
                                       const unsigned short* hbuf,
                                       int cgrp, int pgrp, int l15, int hi,
                                       f32x4 (&acc)[4][4]) {
#pragma unroll
  for (int ks = 0; ks < KSTEPS; ++ks) {
    short8 afr[4], bfr[4];
#pragma unroll
    for (int cf = 0; cf < 4; ++cf) {               // A = W fragments (global, packed)
      int ct = cgrp * 4 + cf;
      afr[cf] = *(const short8*)(wpL + (((((ks * 16 + ct) * 4) + hi) * 16 + l15) << 3));
    }
#pragma unroll
    for (int pf = 0; pf < 4; ++pf) {               // B = h fragments (LDS)
      int p = pgrp * 64 + pf * 16 + l15;
      int byteoff = (p * HSTRIDE + ks * 32 + hi * 8) * 2;
      if (SWZ) byteoff ^= (p & 7) << 4;
      bfr[pf] = *(const short8*)((const char*)hbuf + byteoff);
    }
#pragma unroll
    for (int cf = 0; cf < 4; ++cf)
#pragma unroll
      for (int pf = 0; pf < 4; ++pf)
        acc[cf][pf] = __builtin_amdgcn_mfma_f32_16x16x32_bf16(
            afr[cf], bfr[pf], acc[cf][pf], 0, 0, 0);
  }
}

// epilogue for layers 1,2: bias+relu -> bf16 -> swizzled h buffer (b64 writes)
__device__ __forceinline__ void epi_h(f32x4 (&acc)[4][4], unsigned short* dst,
                                      const float* bv,
                                      int cgrp, int pgrp, int l15, int hi) {
#pragma unroll
  for (int cf = 0; cf < 4; ++cf) {
    int c0 = cgrp * 64 + cf * 16 + hi * 4;         // 4 consecutive channels
    float b0 = bv[c0], b1 = bv[c0 + 1], b2 = bv[c0 + 2], b3 = bv[c0 + 3];
#pragma unroll
    for (int pf = 0; pf < 4; ++pf) {
      int p = pgrp * 64 + pf * 16 + l15;
      f32x4 a = acc[cf][pf];
      unsigned long long w =
            (unsigned long long)f2bf(fmaxf(a[0] + b0, 0.0f))
          | ((unsigned long long)f2bf(fmaxf(a[1] + b1, 0.0f)) << 16)
          | ((unsigned long long)f2bf(fmaxf(a[2] + b2, 0.0f)) << 32)
          | ((unsigned long long)f2bf(fmaxf(a[3] + b3, 0.0f)) << 48);
      int byteoff = ((p * 256 + c0) * 2) ^ ((p & 7) << 4);
      *(unsigned long long*)((char*)dst + byteoff) = w;
    }
  }
}

__global__ __launch_bounds__(THREADS, 1) void pn_main(
    const float* __restrict__ feat,
    const unsigned short* __restrict__ wp,
    const float* __restrict__ b1,
    const float* __restrict__ b2,
    const float* __restrict__ b3,
    const float* __restrict__ cW,
    float* __restrict__ out) {
  __shared__ unsigned short hA[128 * 256];   // 64 KB, swizzled bf16 h1
  __shared__ unsigned short hB[128 * 256];   // 64 KB, swizzled bf16 h2
  __shared__ unsigned short hF[128 * 40];    // 10 KB, feat as B-frag, stride 40
  __shared__ float fRaw[128 * 6];            // 3 KB
  __shared__ float biasL[3 * 256];           // 3 KB
  __shared__ float whL[256];                 // 1 KB  (cW[6..261])
  __shared__ float sPart[4][128];            // 2 KB

  const int tid  = threadIdx.x;
  const int lane = tid & 63;
  const int wave = tid >> 6;
  const int l15  = lane & 15;
  const int hi   = lane >> 4;
  const int cgrp = wave & 3;     // channel group (64 of 256)
  const int pgrp = wave >> 2;    // point group (64 of 128)

  const int blk = blockIdx.x;
  const int m   = blk >> 6;
  const int n0  = (blk & 63) << 7;
  const int g0  = m * 8192 + n0;

  // ---- stage feat tile + biases + classifier hidden weights
  for (int i = tid; i < 768; i += THREADS) fRaw[i] = feat[g0 * 6 + i];
  if (tid < 256) {
    biasL[tid]       = b1[tid];
    biasL[256 + tid] = b2[tid];
    biasL[512 + tid] = b3[tid];
    whL[tid]         = cW[6 + tid];
  }
  __syncthreads();

  // ---- build hF: [p][32] bf16 (k>=6 zero), row stride 40 elems (80 B)
  {
    int p = tid >> 2, ch = tid & 3;
    short8 vv;
#pragma unroll
    for (int jj = 0; jj < 8; ++jj) {
      int k = ch * 8 + jj;
      vv[jj] = (k < 6) ? (short)f2bf(fRaw[p * 6 + k]) : (short)0;
    }
    *(short8*)(hF + p * 40 + ch * 8) = vv;
  }
  __syncthreads();

  f32x4 acc[4][4];
  const f32x4 zz = {0.f, 0.f, 0.f, 0.f};

  // ---- layer 1: K padded to 32, 1 kstep
#pragma unroll
  for (int a = 0; a < 4; ++a)
#pragma unroll
    for (int b = 0; b < 4; ++b) acc[a][b] = zz;
  gemm_T<1, 40, false>(wp + 0, hF, cgrp, pgrp, l15, hi, acc);
  epi_h(acc, hA, biasL + 0, cgrp, pgrp, l15, hi);
  __syncthreads();

  // ---- layer 2
#pragma unroll
  for (int a = 0; a < 4; ++a)
#pragma unroll
    for (int b = 0; b < 4; ++b) acc[a][b] = zz;
  gemm_T<8, 256, true>(wp + 8192, hA, cgrp, pgrp, l15, hi, acc);
  epi_h(acc, hB, biasL + 256, cgrp, pgrp, l15, hi);
  __syncthreads();

  // ---- layer 3 + classifier dot
#pragma unroll
  for (int a = 0; a < 4; ++a)
#pragma unroll
    for (int b = 0; b < 4; ++b) acc[a][b] = zz;
  gemm_T<8, 256, true>(wp + 73728, hB, cgrp, pgrp, l15, hi, acc);

  float part[4] = {0.f, 0.f, 0.f, 0.f};
#pragma unroll
  for (int cf = 0; cf < 4; ++cf) {
    int c0 = cgrp * 64 + cf * 16 + hi * 4;
#pragma unroll
    for (int r = 0; r < 4; ++r) {
      int c = c0 + r;
      float bb = biasL[512 + c];
      float wv = whL[c];
#pragma unroll
      for (int pf = 0; pf < 4; ++pf)
        part[pf] += fmaxf(acc[cf][pf][r] + bb, 0.0f) * wv;
    }
  }
  // reduce across the 4 hi-groups (different channels, same point)
#pragma unroll
  for (int off = 16; off < 64; off <<= 1)
#pragma unroll
    for (int pf = 0; pf < 4; ++pf)
      part[pf] += __shfl_xor(part[pf], off);
  if (hi == 0) {
#pragma unroll
    for (int pf = 0; pf < 4; ++pf)
      sPart[cgrp][pgrp * 64 + pf * 16 + l15] = part[pf];
  }
  __syncthreads();

  if (tid < 128) {
    int p = tid;
    float s = sPart[0][p] + sPart[1][p] + sPart[2][p] + sPart[3][p];
#pragma unroll
    for (int i = 0; i < 6; ++i) s += fRaw[p * 6 + i] * cW[i];
    out[g0 + p] = s;   // raw s1; rescaled by pn_finalize
  }
}

// ---------------------------------------------------------------------------
// k2: per-bbox min/max rescale to [-1,1], in place.
// ---------------------------------------------------------------------------
__global__ void pn_finalize(float* __restrict__ out) {
  __shared__ float smn[4], smx[4];
  int mrow = blockIdx.x;
  float* row = out + mrow * 8192;
  float v[32];
  float mn = 1e30f, mx = -1e30f;
#pragma unroll
  for (int i = 0; i < 32; ++i) {
    v[i] = row[threadIdx.x + i * 256];
    mn = fminf(mn, v[i]);
    mx = fmaxf(mx, v[i]);
  }
#pragma unroll
  for (int off = 1; off < 64; off <<= 1) {
    mn = fminf(mn, __shfl_xor(mn, off));
    mx = fmaxf(mx, __shfl_xor(mx, off));
  }
  int w = threadIdx.x >> 6;
  if ((threadIdx.x & 63) == 0) { smn[w] = mn; smx[w] = mx; }
  __syncthreads();
  mn = fminf(fminf(smn[0], smn[1]), fminf(smn[2], smn[3]));
  mx = fmaxf(fmaxf(smx[0], smx[1]), fmaxf(smx[2], smx[3]));
  float sc = 2.0f / (mx - mn);
#pragma unroll
  for (int i = 0; i < 32; ++i)
    row[threadIdx.x + i * 256] = (v[i] - mn) * sc - 1.0f;
}

// ---------------------------------------------------------------------------
extern "C" void kernel_launch(void* const* d_in, const int* in_sizes, int n_in,
                              void* d_out, int out_size, void* d_ws, size_t ws_size,
                              hipStream_t stream) {
  const float* feat = (const float*)d_in[0];
  const float* eW1  = (const float*)d_in[1];
  const float* eb1  = (const float*)d_in[2];
  const float* eW2  = (const float*)d_in[3];
  const float* eb2  = (const float*)d_in[4];
  const float* eW3  = (const float*)d_in[5];
  const float* eb3  = (const float*)d_in[6];
  // sW*/sb* (7..12) and cb (14) cancel in the per-row rescale -- unused.
  const float* cW   = (const float*)d_in[13];
  float* out = (float*)d_out;
  unsigned short* wpack = (unsigned short*)d_ws;   // needs 278,528 B of ws

  pn_pack<<<544, 256, 0, stream>>>(eW1, eW2, eW3, wpack);
  pn_main<<<4096, THREADS, 0, stream>>>(feat, wpack, eb1, eb2, eb3, cW, out);
  pn_finalize<<<64, 256, 0, stream>>>(out);
}